// Round 5
// baseline (1197.467 us; speedup 1.0000x reference)
//
#include <hip/hip_runtime.h>
#include <stdint.h>

#define MDIM 8192
#define NDIM 16384
#define KDIM 4096
#define NT   64          // K-steps of BK=64

typedef __attribute__((ext_vector_type(8))) short bf16x8;
typedef __attribute__((ext_vector_type(4))) float f32x4;

__device__ __forceinline__ unsigned short f2bf(float f) {
    unsigned int u = __float_as_uint(f);
    u += 0x7FFFu + ((u >> 16) & 1u);   // RNE; inputs finite/normal
    return (unsigned short)(u >> 16);
}

__device__ __forceinline__ void gload_lds16(const void* g, void* l) {
    __builtin_amdgcn_global_load_lds(
        (const __attribute__((address_space(1))) void*)g,
        (__attribute__((address_space(3))) void*)l,
        16, 0, 0);
}

__device__ __forceinline__ f32x4 MFMA(bf16x8 a, bf16x8 b, f32x4 c) {
    return __builtin_amdgcn_mfma_f32_16x16x32_bf16(a, b, c, 0, 0, 0);
}

// ---------------- conversion kernels ----------------

__global__ __launch_bounds__(256)
void convert_x_kernel(const float* __restrict__ x, unsigned short* __restrict__ xb) {
    const long n8 = (long)MDIM * KDIM / 8;
    long i = (long)blockIdx.x * blockDim.x + threadIdx.x;
    const long stride = (long)gridDim.x * blockDim.x;
    for (; i < n8; i += stride) {
        const float4* p = (const float4*)(x + i * 8);
        float4 a = p[0];
        float4 b = p[1];
        union { unsigned short u[8]; uint4 v; } r;
        r.u[0] = f2bf(a.x); r.u[1] = f2bf(a.y); r.u[2] = f2bf(a.z); r.u[3] = f2bf(a.w);
        r.u[4] = f2bf(b.x); r.u[5] = f2bf(b.y); r.u[6] = f2bf(b.z); r.u[7] = f2bf(b.w);
        *(uint4*)(xb + i * 8) = r.v;
    }
}

__global__ __launch_bounds__(256)
void convert_w_kernel(const int* __restrict__ q, const int* __restrict__ zp,
                      unsigned short* __restrict__ wb) {
    const long n8 = (long)NDIM * KDIM / 8;
    long i = (long)blockIdx.x * blockDim.x + threadIdx.x;
    const long stride = (long)gridDim.x * blockDim.x;
    for (; i < n8; i += stride) {
        const long e = i * 8;
        const int o = (int)(e >> 12);          // KDIM = 4096
        const int z = zp[o];
        const int4* p = (const int4*)(q + e);
        int4 a = p[0];
        int4 b = p[1];
        union { unsigned short u[8]; uint4 v; } r;
        r.u[0] = f2bf((float)(a.x - z)); r.u[1] = f2bf((float)(a.y - z));
        r.u[2] = f2bf((float)(a.z - z)); r.u[3] = f2bf((float)(a.w - z));
        r.u[4] = f2bf((float)(b.x - z)); r.u[5] = f2bf((float)(b.y - z));
        r.u[6] = f2bf((float)(b.z - z)); r.u[7] = f2bf((float)(b.w - z));
        *(uint4*)(wb + e) = r.v;
    }
}

// -------- 256x256 8-wave m201-style 4-phase/K-step MFMA GEMM (T1..T5) --------
// C[m,n] = scale[n] * sum_k A[m,k] * W[n,k]
// LDS: 2 bufs x 4 half-planes x 8192 halfwords = 128 KiB.
//   plane 0: A rows 0-127     plane 1: B rows 0-127
//   plane 2: A rows 128-255   plane 3: B rows 128-255   (each 128r x 64k)
// Within a plane: row r = 8 chunks of 16B, physical slot sc = c ^ (r&7)
// (8-lane read groups hit 8 distinct banks -> conflict-free b128). Linear
// gload_lds dest; inverse permutation on the per-lane GLOBAL source.
//
// Per K-step t: 4 phases, each {ds_read subtile; stage; barrier; lgkmcnt(0);
// sched_barrier; setprio(1); 16 MFMA quadrant; setprio(0); barrier}.
// Reads/phase: 12 (A-top + B-left) / 4 (B-right) / 8 (A-bot) / 0.
// All 4 half-tiles of t+1 staged in phases 0-1; vmcnt(0) at phase-3 start
// (>=2 phases of latency cover; nothing else outstanding -> counted wait).
//
// Block mapping (locality, round-3 verified: FETCH 2.5->0.8 GB): round r =
// 256 concurrent blocks covers ALL 32 A-panels x 8 B-panels; A L3-resident;
// A-panel sharers on one XCD (ii%8 == bm%8).

__global__ __launch_bounds__(512, 2)
void gemm8_kernel(const unsigned short* __restrict__ A,
                  const unsigned short* __restrict__ W,
                  const float* __restrict__ scale,
                  float* __restrict__ C) {
    extern __shared__ unsigned short lds[];   // 65536 halfwords

    const int wg = (int)blockIdx.x;
    const int rr = wg >> 8;                   // round 0..7
    const int ii = wg & 255;
    const int bm = ii & 31;                   // 0..31 (all A-panels each round)
    const int bn = rr * 8 + (ii >> 5);        // 0..63 (8 fresh B-panels/round)

    const int tid  = threadIdx.x;
    const int lane = tid & 63;
    const int wid  = tid >> 6;
    const int wm   = wid >> 2;        // 0..1  (128 rows each)
    const int wn   = wid & 3;         // 0..3  (64 cols each)
    const int l15  = lane & 15;
    const int c16  = lane >> 4;       // 0..3

    // frag read offsets (halfwords) within a half-plane: row r, k-chunk c:
    //   off = r*64 + ((c ^ (r&7)) << 3);  r = i*16+l15 -> r&7 = l15&7
    const int cx   = l15 & 7;
    const int ck0  = ((c16)     ^ cx) << 3;   // kk=0 chunk (c = c16)
    const int ck1  = ((4 | c16) ^ cx) << 3;   // kk=1 chunk (c = 4+c16)
    const int aoff0 = l15 * 64 + ck0;
    const int aoff1 = l15 * 64 + ck1;
    const int boff0 = (wn & 1) * 4096 + aoff0;
    const int boff1 = (wn & 1) * 4096 + aoff1;

    // staging: thread covers plane slots s0 = tid (rows 0-63), s1 = 512+tid
    // (rows 64-127); slot s: row = s>>3, logical chunk c = (s&7)^((s>>3)&7)
    const int s0 = tid, s1 = 512 + tid;
    const int soff0 = (s0 >> 3) * KDIM + ((((s0 & 7) ^ ((s0 >> 3) & 7))) << 3);
    const int soff1 = (s1 >> 3) * KDIM + ((((s1 & 7) ^ ((s1 >> 3) & 7))) << 3);
    const int d0 = s0 * 8, d1 = s1 * 8;

    const unsigned short* Ab  = A + (long)bm * 256 * KDIM;
    const unsigned short* Wb  = W + (long)bn * 256 * KDIM;
    const unsigned short* Ab2 = Ab + (long)128 * KDIM;
    const unsigned short* Wb2 = Wb + (long)128 * KDIM;

#define STAGEH(buf, p, base, kofs)                                                  \
    do {                                                                            \
        gload_lds16((base) + soff0 + (kofs), &lds[(buf) + (p) * 8192 + d0]);        \
        gload_lds16((base) + soff1 + (kofs), &lds[(buf) + (p) * 8192 + d1]);        \
    } while (0)

#define MF16(IB, JB)                                                                \
    _Pragma("unroll")                                                               \
    for (int i_ = 0; i_ < 4; ++i_)                                                  \
        _Pragma("unroll")                                                           \
        for (int j_ = 0; j_ < 2; ++j_)                                              \
            _Pragma("unroll")                                                       \
            for (int kk_ = 0; kk_ < 2; ++kk_)                                       \
                acc[(IB) + i_][(JB) + j_] =                                         \
                    MFMA(aF[i_ * 2 + kk_], bF[((JB) + j_) * 2 + kk_],               \
                         acc[(IB) + i_][(JB) + j_]);

    f32x4 acc[8][4];
#pragma unroll
    for (int i = 0; i < 8; ++i)
#pragma unroll
        for (int j = 0; j < 4; ++j) acc[i][j] = (f32x4){0.f, 0.f, 0.f, 0.f};

    bf16x8 aF[8];   // i(quad-local 0..3) x kk(0..1)
    bf16x8 bF[8];   // j(0..3) x kk(0..1)

    // prologue: stage K-step 0 (4 half-tiles, 8 gloads); wait; barrier
    STAGEH(0, 0, Ab,  0);
    STAGEH(0, 1, Wb,  0);
    STAGEH(0, 2, Ab2, 0);
    STAGEH(0, 3, Wb2, 0);
    asm volatile("s_waitcnt vmcnt(0)" ::: "memory");
    __builtin_amdgcn_s_barrier();

    for (int t = 0; t < NT; ++t) {
        const int cur = (t & 1) << 15;
        const int nxt = cur ^ 32768;
        const unsigned short* pAh = &lds[cur + (wm ? 16384 : 0)];
        const unsigned short* pBh = &lds[cur + 8192 + ((wn >> 1) ? 16384 : 0)];
        const int k1 = (t + 1) << 6;
        const bool pf = (t < NT - 1);

        // ---- phase 0: read A i0-3 (8) + B j0-1 (4); stage Ah0,Bh0(t+1) ----
#pragma unroll
        for (int i = 0; i < 4; ++i) {
            aF[i * 2 + 0] = *(const bf16x8*)&pAh[i * 1024 + aoff0];
            aF[i * 2 + 1] = *(const bf16x8*)&pAh[i * 1024 + aoff1];
        }
#pragma unroll
        for (int j = 0; j < 2; ++j) {
            bF[j * 2 + 0] = *(const bf16x8*)&pBh[j * 1024 + boff0];
            bF[j * 2 + 1] = *(const bf16x8*)&pBh[j * 1024 + boff1];
        }
        if (pf) { STAGEH(nxt, 0, Ab, k1); STAGEH(nxt, 1, Wb, k1); }
        asm volatile("s_waitcnt lgkmcnt(8)" ::: "memory");
        __builtin_amdgcn_s_barrier();
        asm volatile("s_waitcnt lgkmcnt(0)" ::: "memory");
        __builtin_amdgcn_sched_barrier(0);
        __builtin_amdgcn_s_setprio(1);
        MF16(0, 0);
        __builtin_amdgcn_s_setprio(0);
        __builtin_amdgcn_sched_barrier(0);
        __builtin_amdgcn_s_barrier();

        // ---- phase 1: read B j2-3 (4); stage Ah1,Bh1(t+1) ----
#pragma unroll
        for (int j = 2; j < 4; ++j) {
            bF[j * 2 + 0] = *(const bf16x8*)&pBh[j * 1024 + boff0];
            bF[j * 2 + 1] = *(const bf16x8*)&pBh[j * 1024 + boff1];
        }
        if (pf) { STAGEH(nxt, 2, Ab2, k1); STAGEH(nxt, 3, Wb2, k1); }
        __builtin_amdgcn_s_barrier();
        asm volatile("s_waitcnt lgkmcnt(0)" ::: "memory");
        __builtin_amdgcn_sched_barrier(0);
        __builtin_amdgcn_s_setprio(1);
        MF16(0, 2);
        __builtin_amdgcn_s_setprio(0);
        __builtin_amdgcn_sched_barrier(0);
        __builtin_amdgcn_s_barrier();

        // ---- phase 2: read A i4-7 (8) ----
#pragma unroll
        for (int i = 0; i < 4; ++i) {
            aF[i * 2 + 0] = *(const bf16x8*)&pAh[(4 + i) * 1024 + aoff0];
            aF[i * 2 + 1] = *(const bf16x8*)&pAh[(4 + i) * 1024 + aoff1];
        }
        __builtin_amdgcn_s_barrier();
        asm volatile("s_waitcnt lgkmcnt(0)" ::: "memory");
        __builtin_amdgcn_sched_barrier(0);
        __builtin_amdgcn_s_setprio(1);
        MF16(4, 0);
        __builtin_amdgcn_s_setprio(0);
        __builtin_amdgcn_sched_barrier(0);
        __builtin_amdgcn_s_barrier();

        // ---- phase 3: no reads; counted wait for t+1 (issued ph0/ph1) ----
        if (pf) asm volatile("s_waitcnt vmcnt(0)" ::: "memory");
        __builtin_amdgcn_s_barrier();
        __builtin_amdgcn_sched_barrier(0);
        __builtin_amdgcn_s_setprio(1);
        MF16(4, 2);
        __builtin_amdgcn_s_setprio(0);
        __builtin_amdgcn_sched_barrier(0);
        __builtin_amdgcn_s_barrier();
    }
#undef STAGEH
#undef MF16

    // ---- epilogue: D mapping col=lane&15, row=(lane>>4)*4+reg (m89-verified) ----
    const long rowA0 = (long)bm * 256;
    const int  colB0 = bn * 256;
#pragma unroll
    for (int j = 0; j < 4; ++j) {
        const int ncol = colB0 + wn * 64 + j * 16 + l15;
        const float s = scale[ncol];
#pragma unroll
        for (int i = 0; i < 8; ++i) {
            float* cp = C + (rowA0 + wm * 128 + i * 16 + c16 * 4) * (long)NDIM + ncol;
#pragma unroll
            for (int r = 0; r < 4; ++r)
                cp[(long)r * NDIM] = acc[i][j][r] * s;
        }
    }
}

// ---------------- safety fallback (no workspace needed, fp32, slow) ----------------

__global__ __launch_bounds__(256)
void fallback_kernel(const float* __restrict__ x, const int* __restrict__ q,
                     const float* __restrict__ scale, const int* __restrict__ zp,
                     float* __restrict__ out) {
    __shared__ float sA[64][17];
    __shared__ float sB[64][17];
    const int bn = (int)blockIdx.x % (NDIM / 64);
    const int bm = (int)blockIdx.x / (NDIM / 64);
    const int t  = threadIdx.x;
    const int tx = t & 15, ty = t >> 4;
    const long rowA = (long)bm * 64, rowB = (long)bn * 64;
    float acc[4][4] = {};
    for (int k0 = 0; k0 < KDIM; k0 += 16) {
#pragma unroll
        for (int i = 0; i < 4; ++i) {
            const int e = t + i * 256;
            const int r = e >> 4, c = e & 15;
            sA[r][c] = x[(rowA + r) * KDIM + k0 + c];
            const int o = (int)rowB + r;
            sB[r][c] = (float)(q[(long)o * KDIM + k0 + c] - zp[o]) * scale[o];
        }
        __syncthreads();
#pragma unroll
        for (int kk = 0; kk < 16; ++kk) {
            float a[4], b[4];
#pragma unroll
            for (int i = 0; i < 4; ++i) a[i] = sA[ty * 4 + i][kk];
#pragma unroll
            for (int j = 0; j < 4; ++j) b[j] = sB[tx * 4 + j][kk];
#pragma unroll
            for (int i = 0; i < 4; ++i)
#pragma unroll
                for (int j = 0; j < 4; ++j) acc[i][j] += a[i] * b[j];
        }
        __syncthreads();
    }
#pragma unroll
    for (int i = 0; i < 4; ++i) {
        const long r = rowA + ty * 4 + i;
#pragma unroll
        for (int j = 0; j < 4; ++j)
            out[r * NDIM + rowB + tx * 4 + j] = acc[i][j];
    }
}

// ---------------- launch ----------------

extern "C" void kernel_launch(void* const* d_in, const int* in_sizes, int n_in,
                              void* d_out, int out_size, void* d_ws, size_t ws_size,
                              hipStream_t stream) {
    const float* x     = (const float*)d_in[0];
    const int*   qw    = (const int*)d_in[1];
    const float* scale = (const float*)d_in[2];
    const int*   zp    = (const int*)d_in[3];
    float*       out   = (float*)d_out;

    const size_t needA = (size_t)MDIM * KDIM * sizeof(unsigned short);  // 64 MiB
    const size_t needW = (size_t)NDIM * KDIM * sizeof(unsigned short);  // 128 MiB

    if (ws_size >= needA + needW) {
        unsigned short* xb = (unsigned short*)d_ws;
        unsigned short* wb = xb + (size_t)MDIM * KDIM;
        convert_x_kernel<<<2048, 256, 0, stream>>>(x, xb);
        convert_w_kernel<<<4096, 256, 0, stream>>>(qw, zp, wb);
        (void)hipFuncSetAttribute((const void*)gemm8_kernel,
                                  hipFuncAttributeMaxDynamicSharedMemorySize, 131072);
        gemm8_kernel<<<(MDIM / 256) * (NDIM / 256), 512, 131072, stream>>>(xb, wb, scale, out);
    } else {
        fallback_kernel<<<(MDIM / 64) * (NDIM / 64), 256, 0, stream>>>(x, qw, scale, zp, out);
    }
}

// Round 6
// 684.158 us; speedup vs baseline: 1.7503x; 1.7503x over previous
//
#include <hip/hip_runtime.h>
#include <stdint.h>

#define MDIM 8192
#define NDIM 16384
#define KDIM 4096
#define NT   64          // K-steps of 64

typedef __attribute__((ext_vector_type(4))) int i32x4;

__device__ __forceinline__ void gload_lds16(const void* g, void* l) {
    __builtin_amdgcn_global_load_lds(
        (const __attribute__((address_space(1))) void*)g,
        (__attribute__((address_space(3))) void*)l,
        16, 0, 0);
}

__device__ __forceinline__ i32x4 MFMA8(i32x4 a, i32x4 b, i32x4 c) {
    return __builtin_amdgcn_mfma_i32_16x16x64_i8(a, b, c, 0, 0, 0);
}

// ---------------- quantization kernels ----------------

// x[8192][4096] fp32 -> int8 with per-row scale sx[m] = rowmax/127 (RNE).
__global__ __launch_bounds__(256)
void quant_x_kernel(const float* __restrict__ x, int8_t* __restrict__ xq,
                    float* __restrict__ sx) {
    const int row = (int)blockIdx.x;
    const float* xr = x + (long)row * KDIM;
    const int t = threadIdx.x;
    float v[16];
#pragma unroll
    for (int i = 0; i < 4; ++i)
        *(float4*)&v[i * 4] = ((const float4*)xr)[t + 256 * i];
    float m = 0.f;
#pragma unroll
    for (int i = 0; i < 16; ++i) m = fmaxf(m, fabsf(v[i]));
#pragma unroll
    for (int off = 32; off >= 1; off >>= 1) m = fmaxf(m, __shfl_xor(m, off));
    __shared__ float red[4];
    if ((t & 63) == 0) red[t >> 6] = m;
    __syncthreads();
    m = fmaxf(fmaxf(red[0], red[1]), fmaxf(red[2], red[3]));
    m = fmaxf(m, 1e-20f);
    const float inv = 127.0f / m;
    if (t == 0) sx[row] = m * (1.0f / 127.0f);
    int* qo = (int*)(xq + (long)row * KDIM);
#pragma unroll
    for (int i = 0; i < 4; ++i) {
        union { int8_t c[4]; int w; } o;
#pragma unroll
        for (int j = 0; j < 4; ++j)
            o.c[j] = (int8_t)__float2int_rn(v[i * 4 + j] * inv);
        qo[t + 256 * i] = o.w;
    }
}

// W: (q - zp) in [-15,15] -> int8, EXACT.
__global__ __launch_bounds__(256)
void quant_w_kernel(const int* __restrict__ q, const int* __restrict__ zp,
                    int8_t* __restrict__ wq) {
    const long i = (long)blockIdx.x * 256 + threadIdx.x;
    const long e = i * 16;
    const int o = (int)(e >> 12);          // KDIM = 4096
    const int z = zp[o];
    union { int8_t c[16]; int4 v; } r;
#pragma unroll
    for (int b = 0; b < 4; ++b) {
        int4 a = ((const int4*)(q + e))[b];
        r.c[b * 4 + 0] = (int8_t)(a.x - z);
        r.c[b * 4 + 1] = (int8_t)(a.y - z);
        r.c[b * 4 + 2] = (int8_t)(a.z - z);
        r.c[b * 4 + 3] = (int8_t)(a.w - z);
    }
    *(int4*)(wq + e) = r.v;
}

// ---------------- 256x256 8-wave int8 MFMA GEMM, triple-buffered ----------------
// C[m,n] = scale[n] * sx[m] * sum_k xq[m,k] * wq[n,k]   (i32 accum, exact)
// LDS: 3 bufs x (A plane 16 KB + B plane 16 KB) = 96 KB.
// Plane: 256 rows x 64 B (one K-step); row = 4 chunks of 16 B, phys slot
// sc = c ^ ((r>>1)&3)  -> any 8 consecutive rows cover all 32 banks for
// b128 reads (conflict-free). Linear gload_lds dest; inverse permutation
// applied to the per-lane GLOBAL source address.
// Schedule: 2 phases/K-step, 16 MFMA each; staging runs 2 K-steps ahead
// (triple buffer) -> vmcnt(2) cover ~= 2 K-steps > HBM latency; ONE
// barrier/K-step, preceded by lgkmcnt(0) (WAR safety) + counted vmcnt.
// Block mapping (locality, round-3 verified): round = 256 concurrent blocks
// covers ALL 32 A-panels x 8 B-panels; all inputs (100 MB int8) L3-resident.

__global__ __launch_bounds__(512, 2)
void gemm_i8_kernel(const int8_t* __restrict__ A, const int8_t* __restrict__ Wt,
                    const float* __restrict__ scale, const float* __restrict__ sx,
                    float* __restrict__ C) {
    __shared__ int8_t lds[3 * 32768];

    const int wg = (int)blockIdx.x;
    const int rr = wg >> 8;                   // round 0..7
    const int ii = wg & 255;
    const int bm = ii & 31;                   // all 32 A-panels each round
    const int bn = rr * 8 + (ii >> 5);        // 8 fresh B-panels per round

    const int tid  = threadIdx.x;
    const int lane = tid & 63;
    const int wid  = tid >> 6;
    const int wm   = wid >> 2;        // 0..1  (128 rows)
    const int wn   = wid & 3;         // 0..3  (64 cols)
    const int l15  = lane & 15;
    const int c16  = lane >> 4;       // 0..3 = logical k-chunk (16 i8 each)

    // fragment byte offset within a plane (row r: fro applied at r*64)
    const int axor = (l15 >> 1) & 3;
    const int fro  = l15 * 64 + ((c16 ^ axor) << 4);

    // staging: thread covers plane slots s0 = tid (rows 0-127), s1 = 512+tid
    const int s0 = tid, s1 = 512 + tid;
    const int soff0 = (s0 >> 2) * KDIM + ((((s0 & 3) ^ ((s0 >> 3) & 3))) << 4);
    const int soff1 = (s1 >> 2) * KDIM + ((((s1 & 3) ^ ((s1 >> 3) & 3))) << 4);
    const int d0 = s0 * 16, d1 = s1 * 16;

    const int8_t* Ab = A  + (long)bm * 256 * KDIM;
    const int8_t* Wb = Wt + (long)bn * 256 * KDIM;

#define STAGE(bb, P, base, tt)                                                      \
    do {                                                                            \
        gload_lds16((base) + soff0 + (tt) * 64, &lds[(bb) + (P) * 16384 + d0]);     \
        gload_lds16((base) + soff1 + (tt) * 64, &lds[(bb) + (P) * 16384 + d1]);     \
    } while (0)

#define RDA(DST, BB, IB)                                                            \
    _Pragma("unroll")                                                               \
    for (int i_ = 0; i_ < 4; ++i_)                                                  \
        DST[i_] = *(const i32x4*)&lds[(BB) + (wm * 128 + ((IB) + i_) * 16) * 64 + fro];

#define RDB(DST, BB)                                                                \
    _Pragma("unroll")                                                               \
    for (int j_ = 0; j_ < 4; ++j_)                                                  \
        DST[j_] = *(const i32x4*)&lds[(BB) + 16384 + (wn * 64 + j_ * 16) * 64 + fro];

#define MFMAQ(IB, AS, BS)                                                           \
    _Pragma("unroll")                                                               \
    for (int i_ = 0; i_ < 4; ++i_)                                                  \
        _Pragma("unroll")                                                           \
        for (int j_ = 0; j_ < 4; ++j_)                                              \
            acc[(IB) + i_][j_] = MFMA8(AS[i_], BS[j_], acc[(IB) + i_][j_]);

    i32x4 acc[8][4];
#pragma unroll
    for (int i = 0; i < 8; ++i)
#pragma unroll
        for (int j = 0; j < 4; ++j) acc[i][j] = (i32x4){0, 0, 0, 0};

    i32x4 aS0[4], aS1[4], bSA[4], bSB[4];
    int b0 = 0, b1 = 32768, b2 = 65536;

    // prologue: stage steps 0 and 1; wait step 0; pre-read phase-A frags
    STAGE(b0, 0, Ab, 0); STAGE(b0, 1, Wb, 0);
    STAGE(b1, 0, Ab, 1); STAGE(b1, 1, Wb, 1);
    asm volatile("s_waitcnt vmcnt(4)" ::: "memory");
    __builtin_amdgcn_s_barrier();
    RDA(aS0, b0, 0);
    RDB(bSA, b0);

#define KSTEP(T, BCUR, BNXT)                                                        \
    do {                                                                            \
        const bool pf_ = (T) < NT - 2;                                              \
        /* phase A: read A i4-7(cur); stage A(T+2); MFMA i0-3 */                    \
        RDA(aS1, b0, 4);                                                            \
        if (pf_) { STAGE(b2, 0, Ab, (T) + 2); }                                     \
        __builtin_amdgcn_sched_barrier(0);                                          \
        __builtin_amdgcn_s_setprio(1);                                              \
        MFMAQ(0, aS0, BCUR);                                                        \
        __builtin_amdgcn_s_setprio(0);                                              \
        __builtin_amdgcn_sched_barrier(0);                                          \
        /* phase B: sync; read A i0-3 + B of T+1; stage B(T+2); MFMA i4-7 */        \
        asm volatile("s_waitcnt lgkmcnt(0)" ::: "memory");                          \
        if (pf_) asm volatile("s_waitcnt vmcnt(2)" ::: "memory");                   \
        else     asm volatile("s_waitcnt vmcnt(0)" ::: "memory");                   \
        __builtin_amdgcn_s_barrier();                                               \
        RDA(aS0, b1, 0);                                                            \
        RDB(BNXT, b1);                                                              \
        if (pf_) { STAGE(b2, 1, Wb, (T) + 2); }                                     \
        __builtin_amdgcn_sched_barrier(0);                                          \
        __builtin_amdgcn_s_setprio(1);                                              \
        MFMAQ(4, aS1, BCUR);                                                        \
        __builtin_amdgcn_s_setprio(0);                                              \
        __builtin_amdgcn_sched_barrier(0);                                          \
        const int tb_ = b0; b0 = b1; b1 = b2; b2 = tb_;                             \
    } while (0)

    for (int t = 0; t < NT; t += 2) {
        KSTEP(t,     bSA, bSB);
        KSTEP(t + 1, bSB, bSA);
    }
#undef KSTEP
#undef STAGE
#undef RDA
#undef RDB
#undef MFMAQ

    // epilogue: D mapping col=lane&15, row=(lane>>4)*4+reg (m89-verified)
    const long rowA0 = (long)bm * 256 + wm * 128;
    const int  colB0 = bn * 256 + wn * 64;
    float scj[4];
#pragma unroll
    for (int j = 0; j < 4; ++j) scj[j] = scale[colB0 + j * 16 + l15];
#pragma unroll
    for (int i = 0; i < 8; ++i) {
        const long rbase = rowA0 + i * 16 + c16 * 4;
        const float4 s4 = *(const float4*)(sx + rbase);
#pragma unroll
        for (int j = 0; j < 4; ++j) {
            float* cp = C + rbase * NDIM + colB0 + j * 16 + l15;
            cp[0 * (long)NDIM] = (float)acc[i][j][0] * scj[j] * s4.x;
            cp[1 * (long)NDIM] = (float)acc[i][j][1] * scj[j] * s4.y;
            cp[2 * (long)NDIM] = (float)acc[i][j][2] * scj[j] * s4.z;
            cp[3 * (long)NDIM] = (float)acc[i][j][3] * scj[j] * s4.w;
        }
    }
}

// ---------------- safety fallback (no workspace needed, fp32, slow) ----------------

__global__ __launch_bounds__(256)
void fallback_kernel(const float* __restrict__ x, const int* __restrict__ q,
                     const float* __restrict__ scale, const int* __restrict__ zp,
                     float* __restrict__ out) {
    __shared__ float sA[64][17];
    __shared__ float sB[64][17];
    const int bn = (int)blockIdx.x % (NDIM / 64);
    const int bm = (int)blockIdx.x / (NDIM / 64);
    const int t  = threadIdx.x;
    const int tx = t & 15, ty = t >> 4;
    const long rowA = (long)bm * 64, rowB = (long)bn * 64;
    float acc[4][4] = {};
    for (int k0 = 0; k0 < KDIM; k0 += 16) {
#pragma unroll
        for (int i = 0; i < 4; ++i) {
            const int e = t + i * 256;
            const int r = e >> 4, c = e & 15;
            sA[r][c] = x[(rowA + r) * KDIM + k0 + c];
            const int o = (int)rowB + r;
            sB[r][c] = (float)(q[(long)o * KDIM + k0 + c] - zp[o]) * scale[o];
        }
        __syncthreads();
#pragma unroll
        for (int kk = 0; kk < 16; ++kk) {
            float a[4], b[4];
#pragma unroll
            for (int i = 0; i < 4; ++i) a[i] = sA[ty * 4 + i][kk];
#pragma unroll
            for (int j = 0; j < 4; ++j) b[j] = sB[tx * 4 + j][kk];
#pragma unroll
            for (int i = 0; i < 4; ++i)
#pragma unroll
                for (int j = 0; j < 4; ++j) acc[i][j] += a[i] * b[j];
        }
        __syncthreads();
    }
#pragma unroll
    for (int i = 0; i < 4; ++i) {
        const long r = rowA + ty * 4 + i;
#pragma unroll
        for (int j = 0; j < 4; ++j)
            out[r * NDIM + rowB + tx * 4 + j] = acc[i][j];
    }
}

// ---------------- launch ----------------

extern "C" void kernel_launch(void* const* d_in, const int* in_sizes, int n_in,
                              void* d_out, int out_size, void* d_ws, size_t ws_size,
                              hipStream_t stream) {
    const float* x     = (const float*)d_in[0];
    const int*   qw    = (const int*)d_in[1];
    const float* scale = (const float*)d_in[2];
    const int*   zp    = (const int*)d_in[3];
    float*       out   = (float*)d_out;

    const size_t needA  = (size_t)MDIM * KDIM;          // 33.5 MB int8
    const size_t needW  = (size_t)NDIM * KDIM;          // 67.1 MB int8
    const size_t needSx = (size_t)MDIM * sizeof(float); // 32 KB

    if (ws_size >= needA + needW + needSx) {
        int8_t* xq = (int8_t*)d_ws;
        int8_t* wq = xq + needA;
        float*  sx = (float*)((char*)d_ws + needA + needW);
        quant_x_kernel<<<MDIM, 256, 0, stream>>>(x, xq, sx);
        quant_w_kernel<<<(NDIM * (KDIM / 16)) / 256, 256, 0, stream>>>(qw, zp, wq);
        gemm_i8_kernel<<<(MDIM / 256) * (NDIM / 256), 512, 0, stream>>>(xq, wq, scale, sx, out);
    } else {
        fallback_kernel<<<(MDIM / 64) * (NDIM / 64), 256, 0, stream>>>(x, qw, scale, zp, out);
    }
}

// Round 7
// 679.012 us; speedup vs baseline: 1.7635x; 1.0076x over previous
//
#include <hip/hip_runtime.h>
#include <stdint.h>

#define MDIM 8192
#define NDIM 16384
#define KDIM 4096
#define NT   64          // K-steps of 64

typedef __attribute__((ext_vector_type(4))) int i32x4;

__device__ __forceinline__ void gload_lds16(const void* g, void* l) {
    __builtin_amdgcn_global_load_lds(
        (const __attribute__((address_space(1))) void*)g,
        (__attribute__((address_space(3))) void*)l,
        16, 0, 0);
}

__device__ __forceinline__ i32x4 MFMA8(i32x4 a, i32x4 b, i32x4 c) {
    return __builtin_amdgcn_mfma_i32_16x16x64_i8(a, b, c, 0, 0, 0);
}

// ---------------- quantization kernels ----------------

// x[8192][4096] fp32 -> int8 with per-row scale sx[m] = rowmax/127 (RNE).
__global__ __launch_bounds__(256)
void quant_x_kernel(const float* __restrict__ x, int8_t* __restrict__ xq,
                    float* __restrict__ sx) {
    const int row = (int)blockIdx.x;
    const float* xr = x + (long)row * KDIM;
    const int t = threadIdx.x;
    float v[16];
#pragma unroll
    for (int i = 0; i < 4; ++i)
        *(float4*)&v[i * 4] = ((const float4*)xr)[t + 256 * i];
    float m = 0.f;
#pragma unroll
    for (int i = 0; i < 16; ++i) m = fmaxf(m, fabsf(v[i]));
#pragma unroll
    for (int off = 32; off >= 1; off >>= 1) m = fmaxf(m, __shfl_xor(m, off));
    __shared__ float red[4];
    if ((t & 63) == 0) red[t >> 6] = m;
    __syncthreads();
    m = fmaxf(fmaxf(red[0], red[1]), fmaxf(red[2], red[3]));
    m = fmaxf(m, 1e-20f);
    const float inv = 127.0f / m;
    if (t == 0) sx[row] = m * (1.0f / 127.0f);
    int* qo = (int*)(xq + (long)row * KDIM);
#pragma unroll
    for (int i = 0; i < 4; ++i) {
        union { int8_t c[4]; int w; } o;
#pragma unroll
        for (int j = 0; j < 4; ++j)
            o.c[j] = (int8_t)__float2int_rn(v[i * 4 + j] * inv);
        qo[t + 256 * i] = o.w;
    }
}

// W: (q - zp) in [-15,15] -> int8, EXACT.
__global__ __launch_bounds__(256)
void quant_w_kernel(const int* __restrict__ q, const int* __restrict__ zp,
                    int8_t* __restrict__ wq) {
    const long i = (long)blockIdx.x * 256 + threadIdx.x;
    const long e = i * 16;
    const int o = (int)(e >> 12);          // KDIM = 4096
    const int z = zp[o];
    union { int8_t c[16]; int4 v; } r;
#pragma unroll
    for (int b = 0; b < 4; ++b) {
        int4 a = ((const int4*)(q + e))[b];
        r.c[b * 4 + 0] = (int8_t)(a.x - z);
        r.c[b * 4 + 1] = (int8_t)(a.y - z);
        r.c[b * 4 + 2] = (int8_t)(a.z - z);
        r.c[b * 4 + 3] = (int8_t)(a.w - z);
    }
    *(int4*)(wq + e) = r.v;
}

// ------- 256x256 8-wave int8 MFMA GEMM, triple-buffered, WAVE-STAGGERED -------
// C[m,n] = scale[n] * sx[m] * sum_k xq[m,k] * wq[n,k]   (i32 accum, exact)
// LDS: 3 bufs x (A plane 16 KB + B plane 16 KB) = 96 KB; XOR chunk swizzle
// (sc = c ^ ((r>>1)&3)) via pre-swizzled global source, linear DMA dest
// (round-6 verified: SQ_LDS_BANK_CONFLICT = 0).
//
// Wave role-split (fixes round-6's serial LDS<->MFMA alternation at 1 blk/CU):
//   group X = waves 0-3 (wm=0), group Y = waves 4-7 (wm=1); one of each per
//   SIMD. Phase A of step t: X ds_reads frags(t) while Y runs MFMA(t-1);
//   phase B: Y reads frags(t) while X runs MFMA(t). Both pipes busy every
//   phase. Per phase: 1 s_barrier; each wave drains lgkmcnt(0) BEFORE the
//   barrier (cross-wave WAR: buffer reads complete before any wave's next-
//   phase DMA into that buffer); vmcnt(4) before phase-A barrier publishes
//   step t's DMA (2-K-step cover). DMA: A(t+2) issued phase A, B(t+2) phase B.
//
// Block mapping (round-3 verified): round = 256 concurrent blocks covers ALL
// 32 A-panels x 8 B-panels; inputs (100 MB int8) L3-resident.

__global__ __launch_bounds__(512, 2)
void gemm_i8_kernel(const int8_t* __restrict__ A, const int8_t* __restrict__ Wt,
                    const float* __restrict__ scale, const float* __restrict__ sx,
                    float* __restrict__ C) {
    __shared__ int8_t lds[3 * 32768];

    const int wg = (int)blockIdx.x;
    const int rr = wg >> 8;                   // round 0..7
    const int ii = wg & 255;
    const int bm = ii & 31;                   // all 32 A-panels each round
    const int bn = rr * 8 + (ii >> 5);        // 8 fresh B-panels per round

    const int tid  = threadIdx.x;
    const int lane = tid & 63;
    const int wid  = tid >> 6;
    const int wm   = wid >> 2;        // 0..1 (128 rows)  == stagger group
    const int wn   = wid & 3;         // 0..3 (64 cols)
    const int l15  = lane & 15;
    const int c16  = lane >> 4;       // 0..3 = logical k-chunk (16 i8)

    // fragment byte offset within a plane
    const int axor = (l15 >> 1) & 3;
    const int fro  = l15 * 64 + ((c16 ^ axor) << 4);

    // staging: thread covers plane slots s0 = tid, s1 = 512+tid
    const int s0 = tid, s1 = 512 + tid;
    const int soff0 = (s0 >> 2) * KDIM + ((((s0 & 3) ^ ((s0 >> 3) & 3))) << 4);
    const int soff1 = (s1 >> 2) * KDIM + ((((s1 & 3) ^ ((s1 >> 3) & 3))) << 4);
    const int d0 = s0 * 16, d1 = s1 * 16;

    const int8_t* Ab = A  + (long)bm * 256 * KDIM;
    const int8_t* Wb = Wt + (long)bn * 256 * KDIM;

#define STAGE(bb, P, base, tt)                                                      \
    do {                                                                            \
        gload_lds16((base) + soff0 + (tt) * 64, &lds[(bb) + (P) * 16384 + d0]);     \
        gload_lds16((base) + soff1 + (tt) * 64, &lds[(bb) + (P) * 16384 + d1]);     \
    } while (0)

#define RDALL(BB)                                                                   \
    do {                                                                            \
        _Pragma("unroll")                                                           \
        for (int i_ = 0; i_ < 8; ++i_)                                              \
            aF[i_] = *(const i32x4*)&lds[(BB) + (wm * 128 + i_ * 16) * 64 + fro];   \
        _Pragma("unroll")                                                           \
        for (int j_ = 0; j_ < 4; ++j_)                                              \
            bF[j_] = *(const i32x4*)&lds[(BB) + 16384 + (wn * 64 + j_ * 16) * 64 + fro]; \
    } while (0)

#define MFMAALL()                                                                   \
    do {                                                                            \
        __builtin_amdgcn_sched_barrier(0);                                          \
        __builtin_amdgcn_s_setprio(1);                                              \
        _Pragma("unroll")                                                           \
        for (int i_ = 0; i_ < 8; ++i_)                                              \
            _Pragma("unroll")                                                       \
            for (int j_ = 0; j_ < 4; ++j_)                                          \
                acc[i_][j_] = MFMA8(aF[i_], bF[j_], acc[i_][j_]);                   \
        __builtin_amdgcn_s_setprio(0);                                              \
        __builtin_amdgcn_sched_barrier(0);                                          \
    } while (0)

    i32x4 acc[8][4];
#pragma unroll
    for (int i = 0; i < 8; ++i)
#pragma unroll
        for (int j = 0; j < 4; ++j) acc[i][j] = (i32x4){0, 0, 0, 0};

    i32x4 aF[8], bF[4];

    // prologue: stage steps 0 and 1 (8 loads/thread total: 4 per step)
    int cb = 0, nb = 32768, fb = 65536;
    STAGE(cb, 0, Ab, 0); STAGE(cb, 1, Wb, 0);
    STAGE(nb, 0, Ab, 1); STAGE(nb, 1, Wb, 1);

    for (int t = 0; t < NT; ++t) {
        const bool st = (t + 2 < NT);

        // ---------------- PHASE A ----------------
        // publish step t (all waves: own-wave vmcnt; lgkm drains prior reads
        // so next DMA into a retired buffer can't race them)
        asm volatile("s_waitcnt lgkmcnt(0)" ::: "memory");
        asm volatile("s_waitcnt vmcnt(4)" ::: "memory");
        __builtin_amdgcn_s_barrier();
        if (st) STAGE(fb, 0, Ab, t + 2);
        if (wm == 0) {
            RDALL(cb);              // X: read frags(t)
        } else if (t > 0) {
            MFMAALL();              // Y: MFMA step t-1
        }

        // ---------------- PHASE B ----------------
        asm volatile("s_waitcnt lgkmcnt(0)" ::: "memory");
        __builtin_amdgcn_s_barrier();
        if (st) STAGE(fb, 1, Wb, t + 2);
        if (wm == 1) {
            RDALL(cb);              // Y: read frags(t)
        } else {
            MFMAALL();              // X: MFMA step t
        }

        const int tmp = cb; cb = nb; nb = fb; fb = tmp;
    }
    if (wm == 1) MFMAALL();         // Y: final step NT-1 (register-only)

#undef STAGE
#undef RDALL
#undef MFMAALL

    // epilogue: D mapping col=lane&15, row=(lane>>4)*4+reg (m89-verified)
    const long rowA0 = (long)bm * 256 + wm * 128;
    const int  colB0 = bn * 256 + wn * 64;
    float scj[4];
#pragma unroll
    for (int j = 0; j < 4; ++j) scj[j] = scale[colB0 + j * 16 + l15];
#pragma unroll
    for (int i = 0; i < 8; ++i) {
        const long rbase = rowA0 + i * 16 + c16 * 4;
        const float4 s4 = *(const float4*)(sx + rbase);
#pragma unroll
        for (int j = 0; j < 4; ++j) {
            float* cp = C + rbase * NDIM + colB0 + j * 16 + l15;
            cp[0 * (long)NDIM] = (float)acc[i][j][0] * scj[j] * s4.x;
            cp[1 * (long)NDIM] = (float)acc[i][j][1] * scj[j] * s4.y;
            cp[2 * (long)NDIM] = (float)acc[i][j][2] * scj[j] * s4.z;
            cp[3 * (long)NDIM] = (float)acc[i][j][3] * scj[j] * s4.w;
        }
    }
}

// ---------------- safety fallback (no workspace needed, fp32, slow) ----------------

__global__ __launch_bounds__(256)
void fallback_kernel(const float* __restrict__ x, const int* __restrict__ q,
                     const float* __restrict__ scale, const int* __restrict__ zp,
                     float* __restrict__ out) {
    __shared__ float sA[64][17];
    __shared__ float sB[64][17];
    const int bn = (int)blockIdx.x % (NDIM / 64);
    const int bm = (int)blockIdx.x / (NDIM / 64);
    const int t  = threadIdx.x;
    const int tx = t & 15, ty = t >> 4;
    const long rowA = (long)bm * 64, rowB = (long)bn * 64;
    float acc[4][4] = {};
    for (int k0 = 0; k0 < KDIM; k0 += 16) {
#pragma unroll
        for (int i = 0; i < 4; ++i) {
            const int e = t + i * 256;
            const int r = e >> 4, c = e & 15;
            sA[r][c] = x[(rowA + r) * KDIM + k0 + c];
            const int o = (int)rowB + r;
            sB[r][c] = (float)(q[(long)o * KDIM + k0 + c] - zp[o]) * scale[o];
        }
        __syncthreads();
#pragma unroll
        for (int kk = 0; kk < 16; ++kk) {
            float a[4], b[4];
#pragma unroll
            for (int i = 0; i < 4; ++i) a[i] = sA[ty * 4 + i][kk];
#pragma unroll
            for (int j = 0; j < 4; ++j) b[j] = sB[tx * 4 + j][kk];
#pragma unroll
            for (int i = 0; i < 4; ++i)
#pragma unroll
                for (int j = 0; j < 4; ++j) acc[i][j] += a[i] * b[j];
        }
        __syncthreads();
    }
#pragma unroll
    for (int i = 0; i < 4; ++i) {
        const long r = rowA + ty * 4 + i;
#pragma unroll
        for (int j = 0; j < 4; ++j)
            out[r * NDIM + rowB + tx * 4 + j] = acc[i][j];
    }
}

// ---------------- launch ----------------

extern "C" void kernel_launch(void* const* d_in, const int* in_sizes, int n_in,
                              void* d_out, int out_size, void* d_ws, size_t ws_size,
                              hipStream_t stream) {
    const float* x     = (const float*)d_in[0];
    const int*   qw    = (const int*)d_in[1];
    const float* scale = (const float*)d_in[2];
    const int*   zp    = (const int*)d_in[3];
    float*       out   = (float*)d_out;

    const size_t needA  = (size_t)MDIM * KDIM;          // 33.5 MB int8
    const size_t needW  = (size_t)NDIM * KDIM;          // 67.1 MB int8
    const size_t needSx = (size_t)MDIM * sizeof(float); // 32 KB

    if (ws_size >= needA + needW + needSx) {
        int8_t* xq = (int8_t*)d_ws;
        int8_t* wq = xq + needA;
        float*  sx = (float*)((char*)d_ws + needA + needW);
        quant_x_kernel<<<MDIM, 256, 0, stream>>>(x, xq, sx);
        quant_w_kernel<<<(NDIM * (KDIM / 16)) / 256, 256, 0, stream>>>(qw, zp, wq);
        gemm_i8_kernel<<<(MDIM / 256) * (NDIM / 256), 512, 0, stream>>>(xq, wq, scale, sx, out);
    } else {
        fallback_kernel<<<(MDIM / 64) * (NDIM / 64), 256, 0, stream>>>(x, qw, scale, zp, out);
    }
}